// Round 5
// baseline (221.351 us; speedup 1.0000x reference)
//
#include <hip/hip_runtime.h>
#include <hip/hip_fp16.h>

typedef unsigned int u32;
typedef unsigned short u16;
typedef _Float16 f16x8 __attribute__((ext_vector_type(8)));
typedef float f32x4 __attribute__((ext_vector_type(4)));

#define OUT_F 8192
#define IN_F 8192
#define TOKENS 256
#define N_GROUPS 524288
#define SPLITK 4
#define KSPAN (IN_F / SPLITK)   // 2048 weights per row-split
#define KT (KSPAN / 64)         // 32 K-iterations

// workspace layout
#define XB_OFF 0
#define T_OFF ((size_t)TOKENS * IN_F * 2)                 // 4 MiB
#define NF_OFF (T_OFF + 65536)
#define PART_OFF (NF_OFF + (size_t)N_GROUPS * 2)          // +1 MiB
#define PART_BYTES ((size_t)SPLITK * TOKENS * OUT_F * 4)  // 32 MiB
#define WS_NEED (PART_OFF + PART_BYTES)

// ---------------------------------------------------------------------------
// prep: fused normcvt + prep1 (R0 version).
// ---------------------------------------------------------------------------
__global__ __launch_bounds__(256) void prep(const void* __restrict__ wn,
                                            __half* __restrict__ nf,
                                            const float* __restrict__ x,
                                            const float* __restrict__ la,
                                            u16* __restrict__ xb,
                                            float* __restrict__ t) {
  int tid = threadIdx.x;
  if (blockIdx.x < 512) {
    __shared__ int votes[3];
    if (tid < 3) votes[tid] = 0;
    __syncthreads();
    const u16* pu = (const u16*)wn;
    const u32* pw = (const u32*)wn;
    int v16 = 0, vbf = 0, vf = 0;
    for (int i = tid; i < 2048; i += 256) {
      u16 u = pu[i];
      float h = __half2float(__builtin_bit_cast(__half, u));
      float b = __builtin_bit_cast(float, ((u32)u) << 16);
      if (h > 0.008f && h < 1.002f) v16++;
      if (b > 0.008f && b < 1.002f) vbf++;
    }
    for (int i = tid; i < 1024; i += 256) {
      float f = __builtin_bit_cast(float, pw[i]);
      if (f > 0.008f && f < 1.002f) vf++;
    }
    atomicAdd(&votes[0], v16);
    atomicAdd(&votes[1], vbf);
    atomicAdd(&votes[2], vf);
    __syncthreads();
    int a16 = votes[0], abf = votes[1], af32 = 2 * votes[2];
    int mode = (a16 >= abf && a16 >= af32) ? 0 : (abf >= af32 ? 1 : 2);
#pragma unroll
    for (int i = 0; i < 4; ++i) {
      int g = blockIdx.x * 1024 + i * 256 + tid;
      float v;
      if (mode == 0) v = __half2float(((const __half*)wn)[g]);
      else if (mode == 1) v = __builtin_bit_cast(float, ((u32)((const u16*)wn)[g]) << 16);
      else v = ((const float*)wn)[g];
      nf[g] = __float2half(v);
    }
    return;
  }
  int b2 = blockIdx.x - 512;
  int m = b2 & 255;
  int half = b2 >> 8;
  const float4* xr = (const float4*)(x + (size_t)m * IN_F);
  u32* xbr = (u32*)(xb + (size_t)m * IN_F);
  float pl[16];
#pragma unroll
  for (int r = 0; r < 16; ++r) pl[r] = 0.f;
#pragma unroll
  for (int it = 0; it < 4; ++it) {
    int k4 = half * 1024 + it * 256 + tid;
    float4 xv = xr[k4];
    u32 p0 = __builtin_bit_cast(u32, __float22half2_rn(make_float2(xv.x, xv.y)));
    u32 p1 = __builtin_bit_cast(u32, __float22half2_rn(make_float2(xv.z, xv.w)));
    ((uint2*)xbr)[k4] = make_uint2(p0, p1);
#pragma unroll
    for (int r = 0; r < 16; ++r) {
      const float4 av = ((const float4*)(la + (size_t)r * IN_F))[k4];
      pl[r] = fmaf(xv.x, av.x, pl[r]);
      pl[r] = fmaf(xv.y, av.y, pl[r]);
      pl[r] = fmaf(xv.z, av.z, pl[r]);
      pl[r] = fmaf(xv.w, av.w, pl[r]);
    }
  }
#pragma unroll
  for (int r = 0; r < 16; ++r) {
    float v = pl[r];
#pragma unroll
    for (int d = 32; d > 0; d >>= 1) v += __shfl_xor(v, d);
    pl[r] = v;
  }
  __shared__ float red[4][16];
  int wave = tid >> 6, lane = tid & 63;
  if (lane == 0) {
#pragma unroll
    for (int r = 0; r < 16; ++r) red[wave][r] = pl[r];
  }
  __syncthreads();
  if (tid < 16)
    t[((size_t)half * TOKENS + m) * 16 + tid] =
        red[0][tid] + red[1][tid] + red[2][tid] + red[3][tid];
}

// ---------------------------------------------------------------------------
// prep2 (fallback path only): d_out = bias + lora (atomic reduction target).
// ---------------------------------------------------------------------------
__global__ __launch_bounds__(256) void prep2(const float* __restrict__ t,
                                             const float* __restrict__ lb,
                                             const float* __restrict__ bias,
                                             float* __restrict__ out) {
  __shared__ float tS[16 * 16];
  int tid = threadIdx.x;
  int n = blockIdx.x * 256 + tid;
  int mbase = blockIdx.y * 16;
  if (tid < 64) {
    float4 a = ((const float4*)(t + (size_t)mbase * 16))[tid];
    float4 b = ((const float4*)(t + (size_t)TOKENS * 16 + (size_t)mbase * 16))[tid];
    ((float4*)tS)[tid] = make_float4(a.x + b.x, a.y + b.y, a.z + b.z, a.w + b.w);
  }
  const float4* lbp = (const float4*)(lb + (size_t)n * 16);
  float4 b0 = lbp[0], b1 = lbp[1], b2 = lbp[2], b3 = lbp[3];
  float bv = bias[n];
  __syncthreads();
#pragma unroll
  for (int mm = 0; mm < 16; ++mm) {
    const float* tr = &tS[mm * 16];
    float a = bv;
    a += tr[0] * b0.x + tr[1] * b0.y + tr[2] * b0.z + tr[3] * b0.w;
    a += tr[4] * b1.x + tr[5] * b1.y + tr[6] * b1.z + tr[7] * b1.w;
    a += tr[8] * b2.x + tr[9] * b2.y + tr[10] * b2.z + tr[11] * b2.w;
    a += tr[12] * b3.x + tr[13] * b3.y + tr[14] * b3.z + tr[15] * b3.w;
    out[(size_t)(mbase + mm) * OUT_F + n] = a;
  }
}

// ---------------------------------------------------------------------------
// finish (partial path): out = bias + lora + sum_kz partials. No atomics.
// ---------------------------------------------------------------------------
__global__ __launch_bounds__(256) void finish(const float* __restrict__ t,
                                              const float* __restrict__ lb,
                                              const float* __restrict__ bias,
                                              const float* __restrict__ part,
                                              float* __restrict__ out) {
  __shared__ float tS[16 * 16];
  int tid = threadIdx.x;
  int n = blockIdx.x * 256 + tid;
  int mbase = blockIdx.y * 16;
  if (tid < 64) {
    float4 a = ((const float4*)(t + (size_t)mbase * 16))[tid];
    float4 b = ((const float4*)(t + (size_t)TOKENS * 16 + (size_t)mbase * 16))[tid];
    ((float4*)tS)[tid] = make_float4(a.x + b.x, a.y + b.y, a.z + b.z, a.w + b.w);
  }
  const float4* lbp = (const float4*)(lb + (size_t)n * 16);
  float4 b0 = lbp[0], b1 = lbp[1], b2 = lbp[2], b3 = lbp[3];
  float bv = bias[n];
  __syncthreads();
#pragma unroll
  for (int mm = 0; mm < 16; ++mm) {
    const float* tr = &tS[mm * 16];
    float a = bv;
    a += tr[0] * b0.x + tr[1] * b0.y + tr[2] * b0.z + tr[3] * b0.w;
    a += tr[4] * b1.x + tr[5] * b1.y + tr[6] * b1.z + tr[7] * b1.w;
    a += tr[8] * b2.x + tr[9] * b2.y + tr[10] * b2.z + tr[11] * b2.w;
    a += tr[12] * b3.x + tr[13] * b3.y + tr[14] * b3.z + tr[15] * b3.w;
    size_t base = (size_t)(mbase + mm) * OUT_F + n;
#pragma unroll
    for (int kz = 0; kz < SPLITK; ++kz)
      a += part[(size_t)kz * TOKENS * OUT_F + base];
    out[base] = a;
  }
}

// ---------------------------------------------------------------------------
// gemm_q2 R10: ZERO-LDS, ZERO-BARRIER register-dequant GEMM.
// R0-R4 accounting: LDS issue pipe was ~83% busy (128 wave-instrs x ~12cyc
// x 2 blocks per CU-iter) while MFMA sat at 22% -- every schedule variant
// failed because all kept the same LDS work. This version removes LDS
// entirely:
//  - wq stores 1 code byte per int32, so one dwordx4 per lane = 4 bytes =
//    16 weights = one B-fragment pair. Dequant is arithmetic, in-register:
//    h2 = 0x40004000 | code<<8 (f16 h = 2+q/2), w2 = v_pk_fma_f16(h2,
//    4n/3, -11n/3) = n*(2q-3)/3. No LUT, no ds_write, no frag re-read.
//  - A (xb, f16, L2-resident 4MB) loaded straight to registers.
//  - k-order is a free permutation if A and B agree: lane q takes
//    k = kt*64 + q*16 + ks*8 + e, so both A and B lane loads are
//    contiguous 16B. Norm group = kz*16 + (kt>>1) uniform per iter.
//  - waves fully independent: no __syncthreads in the kernel at all.
//    Depth-1 prefetch for B codes + norms (X/Y static sets, rule #20);
//    A-load latency hidden behind the ~320cy dequant VALU block + TLP.
// Per-CU-iter budget: MFMA 1242 cyc, VALU ~800, LDS 0 -> MFMA-topped.
// ---------------------------------------------------------------------------
__device__ __forceinline__ __half2 h2u(u32 x) { return __builtin_bit_cast(__half2, x); }

__device__ __forceinline__ f16x8 bfrag(u32 bA, u32 bB, __half2 s, __half2 c) {
  u32 w[4];
  w[0] = __builtin_bit_cast(u32, __hfma2(h2u(0x40004000u | ((bA & 3u) << 8) | ((bA & 0xCu) << 22)), s, c));
  w[1] = __builtin_bit_cast(u32, __hfma2(h2u(0x40004000u | ((bA & 0x30u) << 4) | ((bA & 0xC0u) << 18)), s, c));
  w[2] = __builtin_bit_cast(u32, __hfma2(h2u(0x40004000u | ((bB & 3u) << 8) | ((bB & 0xCu) << 22)), s, c));
  w[3] = __builtin_bit_cast(u32, __hfma2(h2u(0x40004000u | ((bB & 0x30u) << 4) | ((bB & 0xC0u) << 18)), s, c));
  uint4 p = make_uint4(w[0], w[1], w[2], w[3]);
  return __builtin_bit_cast(f16x8, p);
}

__global__ __launch_bounds__(256, 2) void gemm_q2(const u16* __restrict__ xb,
                                                  const int* __restrict__ wq,
                                                  const __half* __restrict__ wn,
                                                  float* __restrict__ dst,
                                                  int mode) {
  int tid = threadIdx.x;
  int n0 = blockIdx.x * 128;
  int m0 = blockIdx.y * 128;
  int kz = blockIdx.z;
  int wave = tid >> 6, lane = tid & 63;
  int q = lane >> 4, l15 = lane & 15;
  int mo = (wave & 1) * 64, no = (wave >> 1) * 64;

  // A row pointers: lane (q,l15) reads 16B at k = kt*64 + q*16 + ks*8
  const u16* ap[4];
#pragma unroll
  for (int mt = 0; mt < 4; ++mt)
    ap[mt] = xb + (size_t)(m0 + mo + mt * 16 + l15) * IN_F + (size_t)kz * KSPAN + q * 16;

  // B code pointers (ints; 1 byte/int): row*2048 + kz*512 + kt*16 + q*4
  const int* bp[4];
  const __half* np[4];
#pragma unroll
  for (int nt = 0; nt < 4; ++nt) {
    int row = n0 + no + nt * 16 + l15;
    bp[nt] = wq + (size_t)row * (IN_F / 4) + (size_t)kz * (KSPAN / 4) + q * 4;
    np[nt] = wn + (size_t)row * (IN_F / 128) + (size_t)kz * (KSPAN / 128);
  }

  f32x4 zero4 = {0.f, 0.f, 0.f, 0.f};
  f32x4 acc[4][4];
#pragma unroll
  for (int i = 0; i < 4; ++i)
#pragma unroll
    for (int j = 0; j < 4; ++j) acc[i][j] = zero4;

  // prefetch: codes(0) -> X, norms(pair 0) -> s2/c2
  int4 cbX[4], cbY[4];
  __half nr[4];
  __half2 s2[4], c2[4];
#pragma unroll
  for (int nt = 0; nt < 4; ++nt) cbX[nt] = *(const int4*)(bp[nt]);
#pragma unroll
  for (int nt = 0; nt < 4; ++nt) nr[nt] = np[nt][0];
#pragma unroll
  for (int nt = 0; nt < 4; ++nt) {
    float f = __half2float(nr[nt]);
    s2[nt] = __float2half2_rn(f * (4.f / 3.f));
    c2[nt] = __float2half2_rn(f * (-11.f / 3.f));
  }

  // one k-tile: load A(KTV), dequant CB, 2x16 MFMA
#define COMPUTE(KTV, CB)                                                       \
  do {                                                                         \
    uint4 av0[4], av1[4];                                                      \
    _Pragma("unroll") for (int mt = 0; mt < 4; ++mt)                           \
        av0[mt] = *(const uint4*)(ap[mt] + (KTV) * 64);                        \
    _Pragma("unroll") for (int mt = 0; mt < 4; ++mt)                           \
        av1[mt] = *(const uint4*)(ap[mt] + (KTV) * 64 + 8);                    \
    f16x8 bf0[4], bf1[4];                                                      \
    _Pragma("unroll") for (int nt = 0; nt < 4; ++nt)                           \
        bf0[nt] = bfrag((u32)CB[nt].x, (u32)CB[nt].y, s2[nt], c2[nt]);         \
    _Pragma("unroll") for (int nt = 0; nt < 4; ++nt)                           \
        bf1[nt] = bfrag((u32)CB[nt].z, (u32)CB[nt].w, s2[nt], c2[nt]);         \
    __builtin_amdgcn_s_setprio(1);                                             \
    _Pragma("unroll") for (int mt = 0; mt < 4; ++mt) {                         \
      f16x8 a0 = __builtin_bit_cast(f16x8, av0[mt]);                           \
      _Pragma("unroll") for (int nt = 0; nt < 4; ++nt)                         \
          acc[mt][nt] = __builtin_amdgcn_mfma_f32_16x16x32_f16(                \
              a0, bf0[nt], acc[mt][nt], 0, 0, 0);                              \
    }                                                                          \
    _Pragma("unroll") for (int mt = 0; mt < 4; ++mt) {                         \
      f16x8 a1 = __builtin_bit_cast(f16x8, av1[mt]);                           \
      _Pragma("unroll") for (int nt = 0; nt < 4; ++nt)                         \
          acc[mt][nt] = __builtin_amdgcn_mfma_f32_16x16x32_f16(                \
              a1, bf1[nt], acc[mt][nt], 0, 0, 0);                              \
    }                                                                          \
    __builtin_amdgcn_s_setprio(0);                                             \
  } while (0)

#pragma unroll 1
  for (int p = 0; p < KT / 2; ++p) {
    int ktA = 2 * p, ktB = 2 * p + 1;
    int kq = (p + 1 < KT / 2) ? (p + 1) : 0;       // next norm pair
    int kn = (ktB + 1 < KT) ? (ktB + 1) : 0;       // next even tile
    // ---- even tile: prefetch codes(ktB)->Y, norms(pair p+1); compute X ----
#pragma unroll
    for (int nt = 0; nt < 4; ++nt) cbY[nt] = *(const int4*)(bp[nt] + ktB * 16);
#pragma unroll
    for (int nt = 0; nt < 4; ++nt) nr[nt] = np[nt][kq];
    COMPUTE(ktA, cbX);
    // ---- odd tile: prefetch codes(kn)->X; compute Y ----
#pragma unroll
    for (int nt = 0; nt < 4; ++nt) cbX[nt] = *(const int4*)(bp[nt] + kn * 16);
    COMPUTE(ktB, cbY);
    // rebuild norm scales for next pair (from nr prefetched above)
#pragma unroll
    for (int nt = 0; nt < 4; ++nt) {
      float f = __half2float(nr[nt]);
      s2[nt] = __float2half2_rn(f * (4.f / 3.f));
      c2[nt] = __float2half2_rn(f * (-11.f / 3.f));
    }
  }
#undef COMPUTE

  // ---- epilogue ----
  // C/D layout: row m = quad*4 + reg, col n = lane&15  [m89/m91 verified]
  if (mode) {
    float* pp = dst + (size_t)kz * TOKENS * OUT_F;
#pragma unroll
    for (int mt = 0; mt < 4; ++mt)
#pragma unroll
      for (int nt = 0; nt < 4; ++nt)
#pragma unroll
        for (int r = 0; r < 4; ++r) {
          int mm = m0 + mo + mt * 16 + q * 4 + r;
          int nn = n0 + no + nt * 16 + l15;
          pp[(size_t)mm * OUT_F + nn] = acc[mt][nt][r];
        }
  } else {
#pragma unroll
    for (int mt = 0; mt < 4; ++mt)
#pragma unroll
      for (int nt = 0; nt < 4; ++nt)
#pragma unroll
        for (int r = 0; r < 4; ++r) {
          int mm = m0 + mo + mt * 16 + q * 4 + r;
          int nn = n0 + no + nt * 16 + l15;
          atomicAdd(&dst[(size_t)mm * OUT_F + nn], acc[mt][nt][r]);
        }
  }
}

extern "C" void kernel_launch(void* const* d_in, const int* in_sizes, int n_in,
                              void* d_out, int out_size, void* d_ws, size_t ws_size,
                              hipStream_t stream) {
  (void)in_sizes; (void)n_in; (void)out_size;
  const float* x = (const float*)d_in[0];
  const int* wq = (const int*)d_in[1];
  const void* wn_raw = d_in[2];
  const float* bias = (const float*)d_in[3];
  const float* la = (const float*)d_in[4];
  const float* lb = (const float*)d_in[5];
  float* out = (float*)d_out;

  u16* xb = (u16*)((char*)d_ws + XB_OFF);
  float* t = (float*)((char*)d_ws + T_OFF);
  __half* nf = (__half*)((char*)d_ws + NF_OFF);
  float* part = (float*)((char*)d_ws + PART_OFF);
  int usep = ws_size >= WS_NEED;  // constant per deployment -> graph-safe

  prep<<<1024, 256, 0, stream>>>(wn_raw, nf, x, la, xb, t);
  if (usep) {
    gemm_q2<<<dim3(OUT_F / 128, TOKENS / 128, SPLITK), 256, 0, stream>>>(xb, wq, nf, part, 1);
    finish<<<dim3(OUT_F / 256, TOKENS / 16), 256, 0, stream>>>(t, lb, bias, part, out);
  } else {
    prep2<<<dim3(OUT_F / 256, TOKENS / 16), 256, 0, stream>>>(t, lb, bias, out);
    gemm_q2<<<dim3(OUT_F / 128, TOKENS / 128, SPLITK), 256, 0, stream>>>(xb, wq, nf, out, 0);
  }
}

// Round 6
// 184.602 us; speedup vs baseline: 1.1991x; 1.1991x over previous
//
#include <hip/hip_runtime.h>
#include <hip/hip_fp16.h>

typedef unsigned int u32;
typedef unsigned short u16;
typedef _Float16 f16x8 __attribute__((ext_vector_type(8)));
typedef float f32x4 __attribute__((ext_vector_type(4)));

#define OUT_F 8192
#define IN_F 8192
#define TOKENS 256
#define N_GROUPS 524288
#define SPLITK 4
#define KSPAN (IN_F / SPLITK)   // 2048 weights per row-split
#define KT (KSPAN / 64)         // 32 K-iterations

// workspace layout
#define XB_OFF 0
#define T_OFF ((size_t)TOKENS * IN_F * 2)                 // 4 MiB
#define NF_OFF (T_OFF + 65536)
#define PART_OFF (NF_OFF + (size_t)N_GROUPS * 2)          // +1 MiB
#define PART_BYTES ((size_t)SPLITK * TOKENS * OUT_F * 4)  // 32 MiB
#define WS_NEED (PART_OFF + PART_BYTES)

// ---------------------------------------------------------------------------
// prep: fused normcvt + prep1 (R0 version, untouched -- proven fastest).
// ---------------------------------------------------------------------------
__global__ __launch_bounds__(256) void prep(const void* __restrict__ wn,
                                            __half* __restrict__ nf,
                                            const float* __restrict__ x,
                                            const float* __restrict__ la,
                                            u16* __restrict__ xb,
                                            float* __restrict__ t) {
  int tid = threadIdx.x;
  if (blockIdx.x < 512) {
    __shared__ int votes[3];
    if (tid < 3) votes[tid] = 0;
    __syncthreads();
    const u16* pu = (const u16*)wn;
    const u32* pw = (const u32*)wn;
    int v16 = 0, vbf = 0, vf = 0;
    for (int i = tid; i < 2048; i += 256) {
      u16 u = pu[i];
      float h = __half2float(__builtin_bit_cast(__half, u));
      float b = __builtin_bit_cast(float, ((u32)u) << 16);
      if (h > 0.008f && h < 1.002f) v16++;
      if (b > 0.008f && b < 1.002f) vbf++;
    }
    for (int i = tid; i < 1024; i += 256) {
      float f = __builtin_bit_cast(float, pw[i]);
      if (f > 0.008f && f < 1.002f) vf++;
    }
    atomicAdd(&votes[0], v16);
    atomicAdd(&votes[1], vbf);
    atomicAdd(&votes[2], vf);
    __syncthreads();
    int a16 = votes[0], abf = votes[1], af32 = 2 * votes[2];
    int mode = (a16 >= abf && a16 >= af32) ? 0 : (abf >= af32 ? 1 : 2);
#pragma unroll
    for (int i = 0; i < 4; ++i) {
      int g = blockIdx.x * 1024 + i * 256 + tid;
      float v;
      if (mode == 0) v = __half2float(((const __half*)wn)[g]);
      else if (mode == 1) v = __builtin_bit_cast(float, ((u32)((const u16*)wn)[g]) << 16);
      else v = ((const float*)wn)[g];
      nf[g] = __float2half(v);
    }
    return;
  }
  int b2 = blockIdx.x - 512;
  int m = b2 & 255;
  int half = b2 >> 8;
  const float4* xr = (const float4*)(x + (size_t)m * IN_F);
  u32* xbr = (u32*)(xb + (size_t)m * IN_F);
  float pl[16];
#pragma unroll
  for (int r = 0; r < 16; ++r) pl[r] = 0.f;
#pragma unroll
  for (int it = 0; it < 4; ++it) {
    int k4 = half * 1024 + it * 256 + tid;
    float4 xv = xr[k4];
    u32 p0 = __builtin_bit_cast(u32, __float22half2_rn(make_float2(xv.x, xv.y)));
    u32 p1 = __builtin_bit_cast(u32, __float22half2_rn(make_float2(xv.z, xv.w)));
    ((uint2*)xbr)[k4] = make_uint2(p0, p1);
#pragma unroll
    for (int r = 0; r < 16; ++r) {
      const float4 av = ((const float4*)(la + (size_t)r * IN_F))[k4];
      pl[r] = fmaf(xv.x, av.x, pl[r]);
      pl[r] = fmaf(xv.y, av.y, pl[r]);
      pl[r] = fmaf(xv.z, av.z, pl[r]);
      pl[r] = fmaf(xv.w, av.w, pl[r]);
    }
  }
#pragma unroll
  for (int r = 0; r < 16; ++r) {
    float v = pl[r];
#pragma unroll
    for (int d = 32; d > 0; d >>= 1) v += __shfl_xor(v, d);
    pl[r] = v;
  }
  __shared__ float red[4][16];
  int wave = tid >> 6, lane = tid & 63;
  if (lane == 0) {
#pragma unroll
    for (int r = 0; r < 16; ++r) red[wave][r] = pl[r];
  }
  __syncthreads();
  if (tid < 16)
    t[((size_t)half * TOKENS + m) * 16 + tid] =
        red[0][tid] + red[1][tid] + red[2][tid] + red[3][tid];
}

// ---------------------------------------------------------------------------
// prep2 (fallback path only): d_out = bias + lora (atomic reduction target).
// ---------------------------------------------------------------------------
__global__ __launch_bounds__(256) void prep2(const float* __restrict__ t,
                                             const float* __restrict__ lb,
                                             const float* __restrict__ bias,
                                             float* __restrict__ out) {
  __shared__ float tS[16 * 16];
  int tid = threadIdx.x;
  int n = blockIdx.x * 256 + tid;
  int mbase = blockIdx.y * 16;
  if (tid < 64) {
    float4 a = ((const float4*)(t + (size_t)mbase * 16))[tid];
    float4 b = ((const float4*)(t + (size_t)TOKENS * 16 + (size_t)mbase * 16))[tid];
    ((float4*)tS)[tid] = make_float4(a.x + b.x, a.y + b.y, a.z + b.z, a.w + b.w);
  }
  const float4* lbp = (const float4*)(lb + (size_t)n * 16);
  float4 b0 = lbp[0], b1 = lbp[1], b2 = lbp[2], b3 = lbp[3];
  float bv = bias[n];
  __syncthreads();
#pragma unroll
  for (int mm = 0; mm < 16; ++mm) {
    const float* tr = &tS[mm * 16];
    float a = bv;
    a += tr[0] * b0.x + tr[1] * b0.y + tr[2] * b0.z + tr[3] * b0.w;
    a += tr[4] * b1.x + tr[5] * b1.y + tr[6] * b1.z + tr[7] * b1.w;
    a += tr[8] * b2.x + tr[9] * b2.y + tr[10] * b2.z + tr[11] * b2.w;
    a += tr[12] * b3.x + tr[13] * b3.y + tr[14] * b3.z + tr[15] * b3.w;
    out[(size_t)(mbase + mm) * OUT_F + n] = a;
  }
}

// ---------------------------------------------------------------------------
// finish (partial path): out = bias + lora + sum_kz partials. No atomics.
// ---------------------------------------------------------------------------
__global__ __launch_bounds__(256) void finish(const float* __restrict__ t,
                                              const float* __restrict__ lb,
                                              const float* __restrict__ bias,
                                              const float* __restrict__ part,
                                              float* __restrict__ out) {
  __shared__ float tS[16 * 16];
  int tid = threadIdx.x;
  int n = blockIdx.x * 256 + tid;
  int mbase = blockIdx.y * 16;
  if (tid < 64) {
    float4 a = ((const float4*)(t + (size_t)mbase * 16))[tid];
    float4 b = ((const float4*)(t + (size_t)TOKENS * 16 + (size_t)mbase * 16))[tid];
    ((float4*)tS)[tid] = make_float4(a.x + b.x, a.y + b.y, a.z + b.z, a.w + b.w);
  }
  const float4* lbp = (const float4*)(lb + (size_t)n * 16);
  float4 b0 = lbp[0], b1 = lbp[1], b2 = lbp[2], b3 = lbp[3];
  float bv = bias[n];
  __syncthreads();
#pragma unroll
  for (int mm = 0; mm < 16; ++mm) {
    const float* tr = &tS[mm * 16];
    float a = bv;
    a += tr[0] * b0.x + tr[1] * b0.y + tr[2] * b0.z + tr[3] * b0.w;
    a += tr[4] * b1.x + tr[5] * b1.y + tr[6] * b1.z + tr[7] * b1.w;
    a += tr[8] * b2.x + tr[9] * b2.y + tr[10] * b2.z + tr[11] * b2.w;
    a += tr[12] * b3.x + tr[13] * b3.y + tr[14] * b3.z + tr[15] * b3.w;
    size_t base = (size_t)(mbase + mm) * OUT_F + n;
#pragma unroll
    for (int kz = 0; kz < SPLITK; ++kz)
      a += part[(size_t)kz * TOKENS * OUT_F + base];
    out[base] = a;
  }
}

// ---------------------------------------------------------------------------
// gemm_q2 R11: A-through-LDS (R0's exact staging + 2-barrier rhythm) +
// B dequanted IN REGISTERS (R5's proven bfrag arithmetic) -- no LUT, no Bs.
// Evidence: R4 accounting -- half of R0's 128 LDS wave-instrs/block-iter
// existed only to push B through LDS (32 LUT gathers + 16 B-writes + 32
// B-frag reads); R5 proved register-dequant correctness but lost A-reuse.
// Hybrid keeps A-reuse, drops B's LDS round-trip: LDS = 48 instrs/block-iter
// (16 A-stores + 32 A-frag reads), conflicts -> ~0 (LUT gathers were the
// source).
// k-alignment trick: within a 64-k tile, lane k-group quad covers k-chunk
// quad*16 + ks*8 (any within-tile permutation is legal if A and B agree).
// Then B codes for one lane-tile = ONE int4 (4 code-int32s, 1 byte each =
// 16 weights: .x,.y -> ks=0, .z,.w -> ks=1), and A's LDS chunk index is
// (quad*2+ks)^(row&7). Codes + norms prefetched 1 tile ahead (static X/Y
// register sets, rule #20).
// ---------------------------------------------------------------------------
__device__ __forceinline__ __half2 h2u(u32 x) { return __builtin_bit_cast(__half2, x); }

// one code byte pair -> 8 f16 weights: h = 2 + q/2 (mantissa inject), then
// w = h*(4n/3) - 11n/3 = n*(2q-3)/3  [R5-verified]
__device__ __forceinline__ f16x8 bfrag(u32 bA, u32 bB, __half2 s, __half2 c) {
  u32 w0 = __builtin_bit_cast(u32, __hfma2(h2u(0x40004000u | ((bA & 3u) << 8) | ((bA & 0xCu) << 22)), s, c));
  u32 w1 = __builtin_bit_cast(u32, __hfma2(h2u(0x40004000u | ((bA & 0x30u) << 4) | ((bA & 0xC0u) << 18)), s, c));
  u32 w2 = __builtin_bit_cast(u32, __hfma2(h2u(0x40004000u | ((bB & 3u) << 8) | ((bB & 0xCu) << 22)), s, c));
  u32 w3 = __builtin_bit_cast(u32, __hfma2(h2u(0x40004000u | ((bB & 0x30u) << 4) | ((bB & 0xC0u) << 18)), s, c));
  uint4 p = make_uint4(w0, w1, w2, w3);
  return __builtin_bit_cast(f16x8, p);
}

__global__ __launch_bounds__(256, 2) void gemm_q2(const u16* __restrict__ xb,
                                                  const int* __restrict__ wq,
                                                  const __half* __restrict__ wn,
                                                  float* __restrict__ dst,
                                                  int mode) {
  __shared__ __align__(16) u16 As[128 * 64];  // 16 KiB -- the only LDS

  int tid = threadIdx.x;
  int n0 = blockIdx.x * 128;
  int m0 = blockIdx.y * 128;
  int kz = blockIdx.z;
  int kbase = kz * KSPAN;

  int wave = tid >> 6, lane = tid & 63;
  int quad = lane >> 4, l15 = lane & 15;
  int mo = (wave & 1) * 64, no = (wave >> 1) * 64;

  // A staging (R0 pattern): 1024 16B-chunks, 4/thread; XOR-swizzled source.
  int aslot[4];
  const u16* ag[4];
#pragma unroll
  for (int i = 0; i < 4; ++i) {
    int s = tid + i * 256;
    int mm = s >> 3, c = s & 7;
    int cl = c ^ (mm & 7);
    aslot[i] = s;
    ag[i] = xb + (size_t)(m0 + mm) * IN_F + kbase + cl * 8;
  }

  // B: codes int4 per (nt, tile): int4 index = kt*4 + quad.
  const int4* bp4[4];
  const __half* np[4];
#pragma unroll
  for (int nt = 0; nt < 4; ++nt) {
    int row = n0 + no + nt * 16 + l15;
    bp4[nt] = (const int4*)(wq + (size_t)row * (IN_F / 4) + (size_t)kz * (KSPAN / 4));
    np[nt] = wn + (size_t)row * (IN_F / 128) + (size_t)kz * (KSPAN / 128);
  }

  f32x4 zero4 = {0.f, 0.f, 0.f, 0.f};
  f32x4 acc[4][4];
#pragma unroll
  for (int i = 0; i < 4; ++i)
#pragma unroll
    for (int j = 0; j < 4; ++j) acc[i][j] = zero4;

  // prologue: A(0) -> regs; codes(0) -> X; norms(pair 0) -> scales
  uint4 pa0 = *(const uint4*)(ag[0]);
  uint4 pa1 = *(const uint4*)(ag[1]);
  uint4 pa2 = *(const uint4*)(ag[2]);
  uint4 pa3 = *(const uint4*)(ag[3]);
  int4 cbA[4], cbB[4];
  __half nr[4];
  __half2 s2[4], c2[4];
#pragma unroll
  for (int nt = 0; nt < 4; ++nt) cbA[nt] = bp4[nt][quad];
#pragma unroll
  for (int nt = 0; nt < 4; ++nt) nr[nt] = np[nt][0];
#pragma unroll
  for (int nt = 0; nt < 4; ++nt) {
    float f = __half2float(nr[nt]);
    s2[nt] = __float2half2_rn(f * (4.f / 3.f));
    c2[nt] = __float2half2_rn(f * (-11.f / 3.f));
  }

  // compute one tile from code set CB; A frags from LDS chunk (quad*2+ks)
#define COMPUTE(CB)                                                            \
  do {                                                                         \
    f16x8 af0[4], af1[4];                                                      \
    _Pragma("unroll") for (int mt = 0; mt < 4; ++mt) {                         \
      int row = mo + mt * 16 + l15;                                            \
      af0[mt] = __builtin_bit_cast(                                            \
          f16x8, ((const uint4*)As)[row * 8 + ((quad * 2) ^ (row & 7))]);      \
      af1[mt] = __builtin_bit_cast(                                            \
          f16x8, ((const uint4*)As)[row * 8 + ((quad * 2 + 1) ^ (row & 7))]);  \
    }                                                                          \
    f16x8 bf0[4], bf1[4];                                                      \
    _Pragma("unroll") for (int nt = 0; nt < 4; ++nt) {                         \
      bf0[nt] = bfrag((u32)CB[nt].x, (u32)CB[nt].y, s2[nt], c2[nt]);           \
      bf1[nt] = bfrag((u32)CB[nt].z, (u32)CB[nt].w, s2[nt], c2[nt]);           \
    }                                                                          \
    __builtin_amdgcn_s_setprio(1);                                             \
    _Pragma("unroll") for (int mt = 0; mt < 4; ++mt)                           \
        _Pragma("unroll") for (int nt = 0; nt < 4; ++nt)                       \
            acc[mt][nt] = __builtin_amdgcn_mfma_f32_16x16x32_f16(              \
                af0[mt], bf0[nt], acc[mt][nt], 0, 0, 0);                       \
    _Pragma("unroll") for (int mt = 0; mt < 4; ++mt)                           \
        _Pragma("unroll") for (int nt = 0; nt < 4; ++nt)                       \
            acc[mt][nt] = __builtin_amdgcn_mfma_f32_16x16x32_f16(              \
                af1[mt], bf1[nt], acc[mt][nt], 0, 0, 0);                       \
    __builtin_amdgcn_s_setprio(0);                                             \
  } while (0)

#pragma unroll 1
  for (int p = 0; p < KT / 2; ++p) {
    int ktB = 2 * p + 1;
    int ktN = (ktB + 1 < KT) ? (ktB + 1) : 0;  // next even tile (wrapped)
    int pn = (p + 1 < KT / 2) ? (p + 1) : 0;   // next norm pair (wrapped)

    // ---- even tile (2p): codes in X ----
    __syncthreads();  // all waves done reading As(prev)
    ((uint4*)As)[aslot[0]] = pa0;
    ((uint4*)As)[aslot[1]] = pa1;
    ((uint4*)As)[aslot[2]] = pa2;
    ((uint4*)As)[aslot[3]] = pa3;
    __syncthreads();  // As(2p) visible
    pa0 = *(const uint4*)(ag[0] + ktB * 64);  // A(2p+1)
    pa1 = *(const uint4*)(ag[1] + ktB * 64);
    pa2 = *(const uint4*)(ag[2] + ktB * 64);
    pa3 = *(const uint4*)(ag[3] + ktB * 64);
#pragma unroll
    for (int nt = 0; nt < 4; ++nt) cbB[nt] = bp4[nt][ktB * 4 + quad];  // codes(2p+1)
    COMPUTE(cbA);

    // ---- odd tile (2p+1): codes in Y ----
    __syncthreads();
    ((uint4*)As)[aslot[0]] = pa0;
    ((uint4*)As)[aslot[1]] = pa1;
    ((uint4*)As)[aslot[2]] = pa2;
    ((uint4*)As)[aslot[3]] = pa3;
    __syncthreads();
    pa0 = *(const uint4*)(ag[0] + ktN * 64);  // A(next even)
    pa1 = *(const uint4*)(ag[1] + ktN * 64);
    pa2 = *(const uint4*)(ag[2] + ktN * 64);
    pa3 = *(const uint4*)(ag[3] + ktN * 64);
#pragma unroll
    for (int nt = 0; nt < 4; ++nt) cbA[nt] = bp4[nt][ktN * 4 + quad];  // codes(next even)
#pragma unroll
    for (int nt = 0; nt < 4; ++nt) nr[nt] = np[nt][pn];  // norms(next pair)
    COMPUTE(cbB);

    // rebuild scales for next pair
#pragma unroll
    for (int nt = 0; nt < 4; ++nt) {
      float f = __half2float(nr[nt]);
      s2[nt] = __float2half2_rn(f * (4.f / 3.f));
      c2[nt] = __float2half2_rn(f * (-11.f / 3.f));
    }
  }
#undef COMPUTE

  // ---- epilogue ----
  // C/D layout: row m = quad*4 + reg, col n = lane&15  [m89/m91 verified]
  if (mode) {
    float* pp = dst + (size_t)kz * TOKENS * OUT_F;
#pragma unroll
    for (int mt = 0; mt < 4; ++mt)
#pragma unroll
      for (int nt = 0; nt < 4; ++nt)
#pragma unroll
        for (int r = 0; r < 4; ++r) {
          int mm = m0 + mo + mt * 16 + quad * 4 + r;
          int nn = n0 + no + nt * 16 + l15;
          pp[(size_t)mm * OUT_F + nn] = acc[mt][nt][r];
        }
  } else {
#pragma unroll
    for (int mt = 0; mt < 4; ++mt)
#pragma unroll
      for (int nt = 0; nt < 4; ++nt)
#pragma unroll
        for (int r = 0; r < 4; ++r) {
          int mm = m0 + mo + mt * 16 + quad * 4 + r;
          int nn = n0 + no + nt * 16 + l15;
          atomicAdd(&dst[(size_t)mm * OUT_F + nn], acc[mt][nt][r]);
        }
  }
}

extern "C" void kernel_launch(void* const* d_in, const int* in_sizes, int n_in,
                              void* d_out, int out_size, void* d_ws, size_t ws_size,
                              hipStream_t stream) {
  (void)in_sizes; (void)n_in; (void)out_size;
  const float* x = (const float*)d_in[0];
  const int* wq = (const int*)d_in[1];
  const void* wn_raw = d_in[2];
  const float* bias = (const float*)d_in[3];
  const float* la = (const float*)d_in[4];
  const float* lb = (const float*)d_in[5];
  float* out = (float*)d_out;

  u16* xb = (u16*)((char*)d_ws + XB_OFF);
  float* t = (float*)((char*)d_ws + T_OFF);
  __half* nf = (__half*)((char*)d_ws + NF_OFF);
  float* part = (float*)((char*)d_ws + PART_OFF);
  int usep = ws_size >= WS_NEED;  // constant per deployment -> graph-safe

  prep<<<1024, 256, 0, stream>>>(wn_raw, nf, x, la, xb, t);
  if (usep) {
    gemm_q2<<<dim3(OUT_F / 128, TOKENS / 128, SPLITK), 256, 0, stream>>>(xb, wq, nf, part, 1);
    finish<<<dim3(OUT_F / 256, TOKENS / 16), 256, 0, stream>>>(t, lb, bias, part, out);
  } else {
    prep2<<<dim3(OUT_F / 256, TOKENS / 16), 256, 0, stream>>>(t, lb, bias, out);
    gemm_q2<<<dim3(OUT_F / 128, TOKENS / 128, SPLITK), 256, 0, stream>>>(xb, wq, nf, out, 0);
  }
}

// Round 7
// 182.194 us; speedup vs baseline: 1.2149x; 1.0132x over previous
//
#include <hip/hip_runtime.h>
#include <hip/hip_fp16.h>

typedef unsigned int u32;
typedef unsigned short u16;
typedef _Float16 f16x8 __attribute__((ext_vector_type(8)));
typedef float f32x4 __attribute__((ext_vector_type(4)));

#define OUT_F 8192
#define IN_F 8192
#define TOKENS 256
#define N_GROUPS 524288
#define SPLITK 8
#define KSPAN (IN_F / SPLITK)   // 1024 weights (== bytes of wq per row-split)
#define KT (KSPAN / 64)         // 16 K-iterations

// workspace layout
#define XB_OFF 0
#define T_OFF ((size_t)TOKENS * IN_F * 2)                 // 4 MiB
#define NF_OFF (T_OFF + 65536)
#define PART_OFF (NF_OFF + (size_t)N_GROUPS * 2)          // +1 MiB
#define PART_BYTES ((size_t)SPLITK * TOKENS * OUT_F * 4)  // 64 MiB
#define WS_NEED (PART_OFF + PART_BYTES)

// packed f16 multiply on bit-pattern: 4 weights dequant = 1 LUT read + 2 of these
__device__ __forceinline__ u32 hm2(u32 a, __half2 s) {
  return __builtin_bit_cast(u32, __hmul2(__builtin_bit_cast(__half2, a), s));
}

// ---------------------------------------------------------------------------
// prep: fused normcvt + prep1 (R0 version, untouched -- proven fastest).
// ---------------------------------------------------------------------------
__global__ __launch_bounds__(256) void prep(const void* __restrict__ wn,
                                            __half* __restrict__ nf,
                                            const float* __restrict__ x,
                                            const float* __restrict__ la,
                                            u16* __restrict__ xb,
                                            float* __restrict__ t) {
  int tid = threadIdx.x;
  if (blockIdx.x < 512) {
    __shared__ int votes[3];
    if (tid < 3) votes[tid] = 0;
    __syncthreads();
    const u16* pu = (const u16*)wn;
    const u32* pw = (const u32*)wn;
    int v16 = 0, vbf = 0, vf = 0;
    for (int i = tid; i < 2048; i += 256) {
      u16 u = pu[i];
      float h = __half2float(__builtin_bit_cast(__half, u));
      float b = __builtin_bit_cast(float, ((u32)u) << 16);
      if (h > 0.008f && h < 1.002f) v16++;
      if (b > 0.008f && b < 1.002f) vbf++;
    }
    for (int i = tid; i < 1024; i += 256) {
      float f = __builtin_bit_cast(float, pw[i]);
      if (f > 0.008f && f < 1.002f) vf++;
    }
    atomicAdd(&votes[0], v16);
    atomicAdd(&votes[1], vbf);
    atomicAdd(&votes[2], vf);
    __syncthreads();
    int a16 = votes[0], abf = votes[1], af32 = 2 * votes[2];
    int mode = (a16 >= abf && a16 >= af32) ? 0 : (abf >= af32 ? 1 : 2);
#pragma unroll
    for (int i = 0; i < 4; ++i) {
      int g = blockIdx.x * 1024 + i * 256 + tid;
      float v;
      if (mode == 0) v = __half2float(((const __half*)wn)[g]);
      else if (mode == 1) v = __builtin_bit_cast(float, ((u32)((const u16*)wn)[g]) << 16);
      else v = ((const float*)wn)[g];
      nf[g] = __float2half(v);
    }
    return;
  }
  int b2 = blockIdx.x - 512;
  int m = b2 & 255;
  int half = b2 >> 8;
  const float4* xr = (const float4*)(x + (size_t)m * IN_F);
  u32* xbr = (u32*)(xb + (size_t)m * IN_F);
  float pl[16];
#pragma unroll
  for (int r = 0; r < 16; ++r) pl[r] = 0.f;
#pragma unroll
  for (int it = 0; it < 4; ++it) {
    int k4 = half * 1024 + it * 256 + tid;
    float4 xv = xr[k4];
    u32 p0 = __builtin_bit_cast(u32, __float22half2_rn(make_float2(xv.x, xv.y)));
    u32 p1 = __builtin_bit_cast(u32, __float22half2_rn(make_float2(xv.z, xv.w)));
    ((uint2*)xbr)[k4] = make_uint2(p0, p1);
#pragma unroll
    for (int r = 0; r < 16; ++r) {
      const float4 av = ((const float4*)(la + (size_t)r * IN_F))[k4];
      pl[r] = fmaf(xv.x, av.x, pl[r]);
      pl[r] = fmaf(xv.y, av.y, pl[r]);
      pl[r] = fmaf(xv.z, av.z, pl[r]);
      pl[r] = fmaf(xv.w, av.w, pl[r]);
    }
  }
#pragma unroll
  for (int r = 0; r < 16; ++r) {
    float v = pl[r];
#pragma unroll
    for (int d = 32; d > 0; d >>= 1) v += __shfl_xor(v, d);
    pl[r] = v;
  }
  __shared__ float red[4][16];
  int wave = tid >> 6, lane = tid & 63;
  if (lane == 0) {
#pragma unroll
    for (int r = 0; r < 16; ++r) red[wave][r] = pl[r];
  }
  __syncthreads();
  if (tid < 16)
    t[((size_t)half * TOKENS + m) * 16 + tid] =
        red[0][tid] + red[1][tid] + red[2][tid] + red[3][tid];
}

// ---------------------------------------------------------------------------
// prep2 (fallback path only): d_out = bias + lora (atomic reduction target).
// ---------------------------------------------------------------------------
__global__ __launch_bounds__(256) void prep2(const float* __restrict__ t,
                                             const float* __restrict__ lb,
                                             const float* __restrict__ bias,
                                             float* __restrict__ out) {
  __shared__ float tS[16 * 16];
  int tid = threadIdx.x;
  int n = blockIdx.x * 256 + tid;
  int mbase = blockIdx.y * 16;
  if (tid < 64) {
    float4 a = ((const float4*)(t + (size_t)mbase * 16))[tid];
    float4 b = ((const float4*)(t + (size_t)TOKENS * 16 + (size_t)mbase * 16))[tid];
    ((float4*)tS)[tid] = make_float4(a.x + b.x, a.y + b.y, a.z + b.z, a.w + b.w);
  }
  const float4* lbp = (const float4*)(lb + (size_t)n * 16);
  float4 b0 = lbp[0], b1 = lbp[1], b2 = lbp[2], b3 = lbp[3];
  float bv = bias[n];
  __syncthreads();
#pragma unroll
  for (int mm = 0; mm < 16; ++mm) {
    const float* tr = &tS[mm * 16];
    float a = bv;
    a += tr[0] * b0.x + tr[1] * b0.y + tr[2] * b0.z + tr[3] * b0.w;
    a += tr[4] * b1.x + tr[5] * b1.y + tr[6] * b1.z + tr[7] * b1.w;
    a += tr[8] * b2.x + tr[9] * b2.y + tr[10] * b2.z + tr[11] * b2.w;
    a += tr[12] * b3.x + tr[13] * b3.y + tr[14] * b3.z + tr[15] * b3.w;
    out[(size_t)(mbase + mm) * OUT_F + n] = a;
  }
}

// ---------------------------------------------------------------------------
// finish (partial path): out = bias + lora + sum_kz partials. No atomics.
// ---------------------------------------------------------------------------
__global__ __launch_bounds__(256) void finish(const float* __restrict__ t,
                                              const float* __restrict__ lb,
                                              const float* __restrict__ bias,
                                              const float* __restrict__ part,
                                              float* __restrict__ out) {
  __shared__ float tS[16 * 16];
  int tid = threadIdx.x;
  int n = blockIdx.x * 256 + tid;
  int mbase = blockIdx.y * 16;
  if (tid < 64) {
    float4 a = ((const float4*)(t + (size_t)mbase * 16))[tid];
    float4 b = ((const float4*)(t + (size_t)TOKENS * 16 + (size_t)mbase * 16))[tid];
    ((float4*)tS)[tid] = make_float4(a.x + b.x, a.y + b.y, a.z + b.z, a.w + b.w);
  }
  const float4* lbp = (const float4*)(lb + (size_t)n * 16);
  float4 b0 = lbp[0], b1 = lbp[1], b2 = lbp[2], b3 = lbp[3];
  float bv = bias[n];
  __syncthreads();
#pragma unroll
  for (int mm = 0; mm < 16; ++mm) {
    const float* tr = &tS[mm * 16];
    float a = bv;
    a += tr[0] * b0.x + tr[1] * b0.y + tr[2] * b0.z + tr[3] * b0.w;
    a += tr[4] * b1.x + tr[5] * b1.y + tr[6] * b1.z + tr[7] * b1.w;
    a += tr[8] * b2.x + tr[9] * b2.y + tr[10] * b2.z + tr[11] * b2.w;
    a += tr[12] * b3.x + tr[13] * b3.y + tr[14] * b3.z + tr[15] * b3.w;
    size_t base = (size_t)(mbase + mm) * OUT_F + n;
#pragma unroll
    for (int kz = 0; kz < SPLITK; ++kz)
      a += part[(size_t)kz * TOKENS * OUT_F + base];
    out[base] = a;
  }
}

// ---------------------------------------------------------------------------
// gemm_q2: R0's EXACT kernel (best measured across 7 structural variants:
// 60.5-61 us) with ONE variable changed: SPLITK 4 -> 8.
// R7 model (survives all rounds): per-iter time is a latency chain; it only
// overlaps across INDEPENDENT instruction streams, and streams/CU = BLOCKS/
// CU (waves within a block are barrier-locked into the same phase). R0 was
// grid-capped at 2 blocks/CU (512 blocks exactly; VGPR 72 would allow 7
// waves/SIMD, LDS 34.8K allows 4 blocks). SPLITK=8 -> 1024 blocks -> 4
// independent streams/CU. LDS 34.8K x 4 = 139K < 160K. Cost: +32MB partial
// writes (+~5us HBM), KT=16.
// ---------------------------------------------------------------------------
__global__ __launch_bounds__(256, 1) void gemm_q2(const u16* __restrict__ xb,
                                                  const int* __restrict__ wq,
                                                  const __half* __restrict__ wn,
                                                  float* __restrict__ dst,
                                                  int mode) {
  __shared__ __align__(16) u16 As[128 * 64];
  __shared__ __align__(16) u16 Bs[128 * 64];
  __shared__ uint2 lut[256];

  int tid = threadIdx.x;
  int n0 = blockIdx.x * 128;
  int m0 = blockIdx.y * 128;
  int kz = blockIdx.z;
  int kbase = kz * KSPAN;

  {  // dequant LUT: byte -> 4 f16 unit values {-1,-1/3,1/3,1}
    int b = tid;
    float v0 = (float)(b & 3) * (2.f / 3.f) - 1.f;
    float v1 = (float)((b >> 2) & 3) * (2.f / 3.f) - 1.f;
    float v2 = (float)((b >> 4) & 3) * (2.f / 3.f) - 1.f;
    float v3 = (float)((b >> 6) & 3) * (2.f / 3.f) - 1.f;
    u32 lo = __builtin_bit_cast(u32, __float22half2_rn(make_float2(v0, v1)));
    u32 hi = __builtin_bit_cast(u32, __float22half2_rn(make_float2(v2, v3)));
    lut[b] = make_uint2(lo, hi);
  }

  int wave = tid >> 6, lane = tid & 63;
  int quad = lane >> 4, l15 = lane & 15;
  int mo = (wave & 1) * 64, no = (wave >> 1) * 64;

  // A staging: 1024 16B-chunks, 4 per thread; swizzled slot -> global chunk
  int aslot[4];
  const u16* ag[4];
#pragma unroll
  for (int i = 0; i < 4; ++i) {
    int s = tid + i * 256;
    int mm = s >> 3, c = s & 7;
    int cl = c ^ (mm & 7);
    aslot[i] = s;
    ag[i] = xb + (size_t)(m0 + mm) * IN_F + kbase + cl * 8;
  }

  // B staging: thread -> (row n, half h): 32 consecutive k (32 bytes).
  // wq byte address == flat weight index (each int32 = 1 code byte = 4 wts).
  int bn = tid >> 1, h = tid & 1;
  const char* gB = (const char*)wq + (size_t)(n0 + bn) * IN_F + kbase + h * 32;
  const __half* wnp = wn + (size_t)(n0 + bn) * 64 + kz * (KSPAN / 128);

  f32x4 zero4 = {0.f, 0.f, 0.f, 0.f};
  f32x4 acc[4][4];
#pragma unroll
  for (int i = 0; i < 4; ++i)
#pragma unroll
    for (int j = 0; j < 4; ++j) acc[i][j] = zero4;

  // register prefetch of K-slice 0
  uint4 pa0, pa1, pa2, pa3;
  int4 pb0, pb1;
  __half pn;
  pa0 = *(const uint4*)(ag[0]);
  pa1 = *(const uint4*)(ag[1]);
  pa2 = *(const uint4*)(ag[2]);
  pa3 = *(const uint4*)(ag[3]);
  pb0 = *(const int4*)(gB);
  pb1 = *(const int4*)(gB + 16);
  pn = wnp[0];

#pragma unroll 1
  for (int kt = 0; kt < KT; ++kt) {
    __syncthreads();  // prev mfma done reading LDS (covers LUT on iter 0)

    // ---- store staged A ----
    ((uint4*)As)[aslot[0]] = pa0;
    ((uint4*)As)[aslot[1]] = pa1;
    ((uint4*)As)[aslot[2]] = pa2;
    ((uint4*)As)[aslot[3]] = pa3;

    // ---- dequant + store B ----
    {
      __half2 nh = __half2half2(pn);
      int vv[8] = {pb0.x, pb0.y, pb0.z, pb0.w, pb1.x, pb1.y, pb1.z, pb1.w};
      u32 uu[16];
#pragma unroll
      for (int e = 0; e < 8; ++e) {
        uint2 lv = lut[vv[e] & 255];
        uu[2 * e] = hm2(lv.x, nh);
        uu[2 * e + 1] = hm2(lv.y, nh);
      }
      uint4* Bw = (uint4*)Bs;
#pragma unroll
      for (int cc = 0; cc < 4; ++cc) {
        int pc = (h * 4 + cc) ^ (bn & 7);
        Bw[bn * 8 + pc] = make_uint4(uu[4 * cc], uu[4 * cc + 1], uu[4 * cc + 2], uu[4 * cc + 3]);
      }
    }

    // ---- prefetch next K-slice into regs (overlaps with MFMA below) ----
    if (kt < KT - 1) {
      int ko = (kt + 1) * 64;
      pa0 = *(const uint4*)(ag[0] + ko);
      pa1 = *(const uint4*)(ag[1] + ko);
      pa2 = *(const uint4*)(ag[2] + ko);
      pa3 = *(const uint4*)(ag[3] + ko);
      pb0 = *(const int4*)(gB + ko);
      pb1 = *(const int4*)(gB + ko + 16);
      pn = wnp[(kt + 1) >> 1];
    }
    __syncthreads();

    // ---- compute: 2 k-substeps x (4+4 frags, 16 MFMAs) ----
#pragma unroll
    for (int ks = 0; ks < 2; ++ks) {
      f16x8 af[4], bf[4];
#pragma unroll
      for (int mt = 0; mt < 4; ++mt) {
        int row = mo + mt * 16 + l15;
        int pc = (ks * 4 + quad) ^ (row & 7);
        af[mt] = __builtin_bit_cast(f16x8, ((const uint4*)As)[row * 8 + pc]);
      }
#pragma unroll
      for (int nt = 0; nt < 4; ++nt) {
        int row = no + nt * 16 + l15;
        int pc = (ks * 4 + quad) ^ (row & 7);
        bf[nt] = __builtin_bit_cast(f16x8, ((const uint4*)Bs)[row * 8 + pc]);
      }
#pragma unroll
      for (int mt = 0; mt < 4; ++mt)
#pragma unroll
        for (int nt = 0; nt < 4; ++nt)
          acc[mt][nt] = __builtin_amdgcn_mfma_f32_16x16x32_f16(af[mt], bf[nt], acc[mt][nt], 0, 0, 0);
    }
  }

  // ---- epilogue ----
  // C/D layout: row m = quad*4 + reg, col n = lane&15  [m89/m91 verified]
  if (mode) {
    float* pp = dst + (size_t)kz * TOKENS * OUT_F;
#pragma unroll
    for (int mt = 0; mt < 4; ++mt)
#pragma unroll
      for (int nt = 0; nt < 4; ++nt)
#pragma unroll
        for (int r = 0; r < 4; ++r) {
          int mm = m0 + mo + mt * 16 + quad * 4 + r;
          int nn = n0 + no + nt * 16 + l15;
          pp[(size_t)mm * OUT_F + nn] = acc[mt][nt][r];
        }
  } else {
#pragma unroll
    for (int mt = 0; mt < 4; ++mt)
#pragma unroll
      for (int nt = 0; nt < 4; ++nt)
#pragma unroll
        for (int r = 0; r < 4; ++r) {
          int mm = m0 + mo + mt * 16 + quad * 4 + r;
          int nn = n0 + no + nt * 16 + l15;
          atomicAdd(&dst[(size_t)mm * OUT_F + nn], acc[mt][nt][r]);
        }
  }
}

extern "C" void kernel_launch(void* const* d_in, const int* in_sizes, int n_in,
                              void* d_out, int out_size, void* d_ws, size_t ws_size,
                              hipStream_t stream) {
  (void)in_sizes; (void)n_in; (void)out_size;
  const float* x = (const float*)d_in[0];
  const int* wq = (const int*)d_in[1];
  const void* wn_raw = d_in[2];
  const float* bias = (const float*)d_in[3];
  const float* la = (const float*)d_in[4];
  const float* lb = (const float*)d_in[5];
  float* out = (float*)d_out;

  u16* xb = (u16*)((char*)d_ws + XB_OFF);
  float* t = (float*)((char*)d_ws + T_OFF);
  __half* nf = (__half*)((char*)d_ws + NF_OFF);
  float* part = (float*)((char*)d_ws + PART_OFF);
  int usep = ws_size >= WS_NEED;  // constant per deployment -> graph-safe

  prep<<<1024, 256, 0, stream>>>(wn_raw, nf, x, la, xb, t);
  if (usep) {
    gemm_q2<<<dim3(OUT_F / 128, TOKENS / 128, SPLITK), 256, 0, stream>>>(xb, wq, nf, part, 1);
    finish<<<dim3(OUT_F / 256, TOKENS / 16), 256, 0, stream>>>(t, lb, bias, part, out);
  } else {
    prep2<<<dim3(OUT_F / 256, TOKENS / 16), 256, 0, stream>>>(t, lb, bias, out);
    gemm_q2<<<dim3(OUT_F / 128, TOKENS / 128, SPLITK), 256, 0, stream>>>(xb, wq, nf, out, 0);
  }
}

// Round 8
// 172.762 us; speedup vs baseline: 1.2812x; 1.0546x over previous
//
#include <hip/hip_runtime.h>
#include <hip/hip_fp16.h>

typedef unsigned int u32;
typedef unsigned short u16;
typedef _Float16 f16x8 __attribute__((ext_vector_type(8)));
typedef float f32x4 __attribute__((ext_vector_type(4)));

#define OUT_F 8192
#define IN_F 8192
#define TOKENS 256
#define N_GROUPS 524288
#define SPLITK 8
#define KSPAN (IN_F / SPLITK)   // 1024 weights (== bytes of wq per row-split)
#define KT (KSPAN / 64)         // 16 K-iterations

// workspace layout
#define XB_OFF 0
#define T_OFF ((size_t)TOKENS * IN_F * 2)                 // 4 MiB
#define NF_OFF (T_OFF + 65536)
#define PART_OFF (NF_OFF + (size_t)N_GROUPS * 2)          // +1 MiB
#define PART_BYTES ((size_t)SPLITK * TOKENS * OUT_F * 4)  // 64 MiB
#define WS_NEED (PART_OFF + PART_BYTES)

// packed f16 multiply on bit-pattern: 4 weights dequant = 1 LUT read + 2 of these
__device__ __forceinline__ u32 hm2(u32 a, __half2 s) {
  return __builtin_bit_cast(u32, __hmul2(__builtin_bit_cast(__half2, a), s));
}

// ---------------------------------------------------------------------------
// prep: fused normcvt + prep1 (R0 version, untouched -- proven fastest).
// ---------------------------------------------------------------------------
__global__ __launch_bounds__(256) void prep(const void* __restrict__ wn,
                                            __half* __restrict__ nf,
                                            const float* __restrict__ x,
                                            const float* __restrict__ la,
                                            u16* __restrict__ xb,
                                            float* __restrict__ t) {
  int tid = threadIdx.x;
  if (blockIdx.x < 512) {
    __shared__ int votes[3];
    if (tid < 3) votes[tid] = 0;
    __syncthreads();
    const u16* pu = (const u16*)wn;
    const u32* pw = (const u32*)wn;
    int v16 = 0, vbf = 0, vf = 0;
    for (int i = tid; i < 2048; i += 256) {
      u16 u = pu[i];
      float h = __half2float(__builtin_bit_cast(__half, u));
      float b = __builtin_bit_cast(float, ((u32)u) << 16);
      if (h > 0.008f && h < 1.002f) v16++;
      if (b > 0.008f && b < 1.002f) vbf++;
    }
    for (int i = tid; i < 1024; i += 256) {
      float f = __builtin_bit_cast(float, pw[i]);
      if (f > 0.008f && f < 1.002f) vf++;
    }
    atomicAdd(&votes[0], v16);
    atomicAdd(&votes[1], vbf);
    atomicAdd(&votes[2], vf);
    __syncthreads();
    int a16 = votes[0], abf = votes[1], af32 = 2 * votes[2];
    int mode = (a16 >= abf && a16 >= af32) ? 0 : (abf >= af32 ? 1 : 2);
#pragma unroll
    for (int i = 0; i < 4; ++i) {
      int g = blockIdx.x * 1024 + i * 256 + tid;
      float v;
      if (mode == 0) v = __half2float(((const __half*)wn)[g]);
      else if (mode == 1) v = __builtin_bit_cast(float, ((u32)((const u16*)wn)[g]) << 16);
      else v = ((const float*)wn)[g];
      nf[g] = __float2half(v);
    }
    return;
  }
  int b2 = blockIdx.x - 512;
  int m = b2 & 255;
  int half = b2 >> 8;
  const float4* xr = (const float4*)(x + (size_t)m * IN_F);
  u32* xbr = (u32*)(xb + (size_t)m * IN_F);
  float pl[16];
#pragma unroll
  for (int r = 0; r < 16; ++r) pl[r] = 0.f;
#pragma unroll
  for (int it = 0; it < 4; ++it) {
    int k4 = half * 1024 + it * 256 + tid;
    float4 xv = xr[k4];
    u32 p0 = __builtin_bit_cast(u32, __float22half2_rn(make_float2(xv.x, xv.y)));
    u32 p1 = __builtin_bit_cast(u32, __float22half2_rn(make_float2(xv.z, xv.w)));
    ((uint2*)xbr)[k4] = make_uint2(p0, p1);
#pragma unroll
    for (int r = 0; r < 16; ++r) {
      const float4 av = ((const float4*)(la + (size_t)r * IN_F))[k4];
      pl[r] = fmaf(xv.x, av.x, pl[r]);
      pl[r] = fmaf(xv.y, av.y, pl[r]);
      pl[r] = fmaf(xv.z, av.z, pl[r]);
      pl[r] = fmaf(xv.w, av.w, pl[r]);
    }
  }
#pragma unroll
  for (int r = 0; r < 16; ++r) {
    float v = pl[r];
#pragma unroll
    for (int d = 32; d > 0; d >>= 1) v += __shfl_xor(v, d);
    pl[r] = v;
  }
  __shared__ float red[4][16];
  int wave = tid >> 6, lane = tid & 63;
  if (lane == 0) {
#pragma unroll
    for (int r = 0; r < 16; ++r) red[wave][r] = pl[r];
  }
  __syncthreads();
  if (tid < 16)
    t[((size_t)half * TOKENS + m) * 16 + tid] =
        red[0][tid] + red[1][tid] + red[2][tid] + red[3][tid];
}

// ---------------------------------------------------------------------------
// prep2 (fallback path only): d_out = bias + lora (atomic reduction target).
// ---------------------------------------------------------------------------
__global__ __launch_bounds__(256) void prep2(const float* __restrict__ t,
                                             const float* __restrict__ lb,
                                             const float* __restrict__ bias,
                                             float* __restrict__ out) {
  __shared__ float tS[16 * 16];
  int tid = threadIdx.x;
  int n = blockIdx.x * 256 + tid;
  int mbase = blockIdx.y * 16;
  if (tid < 64) {
    float4 a = ((const float4*)(t + (size_t)mbase * 16))[tid];
    float4 b = ((const float4*)(t + (size_t)TOKENS * 16 + (size_t)mbase * 16))[tid];
    ((float4*)tS)[tid] = make_float4(a.x + b.x, a.y + b.y, a.z + b.z, a.w + b.w);
  }
  const float4* lbp = (const float4*)(lb + (size_t)n * 16);
  float4 b0 = lbp[0], b1 = lbp[1], b2 = lbp[2], b3 = lbp[3];
  float bv = bias[n];
  __syncthreads();
#pragma unroll
  for (int mm = 0; mm < 16; ++mm) {
    const float* tr = &tS[mm * 16];
    float a = bv;
    a += tr[0] * b0.x + tr[1] * b0.y + tr[2] * b0.z + tr[3] * b0.w;
    a += tr[4] * b1.x + tr[5] * b1.y + tr[6] * b1.z + tr[7] * b1.w;
    a += tr[8] * b2.x + tr[9] * b2.y + tr[10] * b2.z + tr[11] * b2.w;
    a += tr[12] * b3.x + tr[13] * b3.y + tr[14] * b3.z + tr[15] * b3.w;
    out[(size_t)(mbase + mm) * OUT_F + n] = a;
  }
}

// ---------------------------------------------------------------------------
// finish (partial path): out = bias + lora + sum_kz partials. No atomics.
// ---------------------------------------------------------------------------
__global__ __launch_bounds__(256) void finish(const float* __restrict__ t,
                                              const float* __restrict__ lb,
                                              const float* __restrict__ bias,
                                              const float* __restrict__ part,
                                              float* __restrict__ out) {
  __shared__ float tS[16 * 16];
  int tid = threadIdx.x;
  int n = blockIdx.x * 256 + tid;
  int mbase = blockIdx.y * 16;
  if (tid < 64) {
    float4 a = ((const float4*)(t + (size_t)mbase * 16))[tid];
    float4 b = ((const float4*)(t + (size_t)TOKENS * 16 + (size_t)mbase * 16))[tid];
    ((float4*)tS)[tid] = make_float4(a.x + b.x, a.y + b.y, a.z + b.z, a.w + b.w);
  }
  const float4* lbp = (const float4*)(lb + (size_t)n * 16);
  float4 b0 = lbp[0], b1 = lbp[1], b2 = lbp[2], b3 = lbp[3];
  float bv = bias[n];
  __syncthreads();
#pragma unroll
  for (int mm = 0; mm < 16; ++mm) {
    const float* tr = &tS[mm * 16];
    float a = bv;
    a += tr[0] * b0.x + tr[1] * b0.y + tr[2] * b0.z + tr[3] * b0.w;
    a += tr[4] * b1.x + tr[5] * b1.y + tr[6] * b1.z + tr[7] * b1.w;
    a += tr[8] * b2.x + tr[9] * b2.y + tr[10] * b2.z + tr[11] * b2.w;
    a += tr[12] * b3.x + tr[13] * b3.y + tr[14] * b3.z + tr[15] * b3.w;
    size_t base = (size_t)(mbase + mm) * OUT_F + n;
#pragma unroll
    for (int kz = 0; kz < SPLITK; ++kz)
      a += part[(size_t)kz * TOKENS * OUT_F + base];
    out[base] = a;
  }
}

// ---------------------------------------------------------------------------
// gemm_q2 R12: BM=256 "all-tokens" tile. The one axis never varied in R0-R7.
// Surviving empirical law: per block-iter time ~ constant (serial chain S +
// MFMA M ~ 4500 cyc) across every schedule/occupancy/LDS variant. With
// BM=128, every weight is dequanted TWICE (once per M-block) and the kernel
// runs 2x the iterations (and barriers) per unit of MFMA. BM=256 doubles
// MFMA per iteration at ~constant S:
//   256x128 tile, 512 thr / 8 waves (4M x 2N of 64x64 -- same 0.5
//   frag-reads/MFMA as R0), SPLITK=8 -> grid 64x1x8 = 512 blocks = 2/CU,
//   KT=16. Per CU vs R0: barriers/2, dequant VALU+LDS /2, code fetch /2,
//   A-staging + frag-read totals equal, MFMA equal.
// Inner iteration is R0's byte-for-byte (LUT dequant, XOR swizzle, reg
// prefetch, 2-barrier rhythm); B-staging per-thread shape is R1's proven
// 4-code-byte variant. LDS 50 KiB -> 2 blocks fit (102 KiB).
// ---------------------------------------------------------------------------
__global__ __launch_bounds__(512, 4) void gemm_q2(const u16* __restrict__ xb,
                                                  const int* __restrict__ wq,
                                                  const __half* __restrict__ wn,
                                                  float* __restrict__ dst,
                                                  int mode) {
  __shared__ __align__(16) u16 As[256 * 64];  // 32 KiB
  __shared__ __align__(16) u16 Bs[128 * 64];  // 16 KiB
  __shared__ uint2 lut[256];

  int tid = threadIdx.x;
  int n0 = blockIdx.x * 128;
  int m0 = blockIdx.y * 256;  // grid.y == 1
  int kz = blockIdx.z;
  int kbase = kz * KSPAN;

  if (tid < 256) {  // dequant LUT: byte -> 4 f16 unit values {-1,-1/3,1/3,1}
    int b = tid;
    float v0 = (float)(b & 3) * (2.f / 3.f) - 1.f;
    float v1 = (float)((b >> 2) & 3) * (2.f / 3.f) - 1.f;
    float v2 = (float)((b >> 4) & 3) * (2.f / 3.f) - 1.f;
    float v3 = (float)((b >> 6) & 3) * (2.f / 3.f) - 1.f;
    u32 lo = __builtin_bit_cast(u32, __float22half2_rn(make_float2(v0, v1)));
    u32 hi = __builtin_bit_cast(u32, __float22half2_rn(make_float2(v2, v3)));
    lut[b] = make_uint2(lo, hi);
  }

  int wave = tid >> 6, lane = tid & 63;
  int quad = lane >> 4, l15 = lane & 15;
  // 8 waves: 4 (m) x 2 (n); each wave owns a 64x64 output sub-tile
  int mo = (wave & 3) * 64, no = (wave >> 2) * 64;

  // A staging: 2048 16B-chunks, 4 per thread; swizzled slot -> global chunk
  int aslot[4];
  const u16* ag[4];
#pragma unroll
  for (int i = 0; i < 4; ++i) {
    int s = tid + i * 512;
    int mm = s >> 3, c = s & 7;
    int cl = c ^ (mm & 7);
    aslot[i] = s;
    ag[i] = xb + (size_t)(m0 + mm) * IN_F + kbase + cl * 8;
  }

  // B staging: thread -> (row bn, quarter q): 16 consecutive k (16 bytes =
  // 4 code-int32s). wq byte address == flat weight index.
  int bn = tid >> 2, q = tid & 3;
  const char* gB = (const char*)wq + (size_t)(n0 + bn) * IN_F + kbase + q * 16;
  const __half* wnp = wn + (size_t)(n0 + bn) * 64 + kz * (KSPAN / 128);

  f32x4 zero4 = {0.f, 0.f, 0.f, 0.f};
  f32x4 acc[4][4];
#pragma unroll
  for (int i = 0; i < 4; ++i)
#pragma unroll
    for (int j = 0; j < 4; ++j) acc[i][j] = zero4;

  // register prefetch of K-slice 0
  uint4 pa0, pa1, pa2, pa3;
  int4 pb;
  __half pn;
  pa0 = *(const uint4*)(ag[0]);
  pa1 = *(const uint4*)(ag[1]);
  pa2 = *(const uint4*)(ag[2]);
  pa3 = *(const uint4*)(ag[3]);
  pb = *(const int4*)(gB);
  pn = wnp[0];

#pragma unroll 1
  for (int kt = 0; kt < KT; ++kt) {
    __syncthreads();  // prev mfma done reading LDS (covers LUT on iter 0)

    // ---- store staged A ----
    ((uint4*)As)[aslot[0]] = pa0;
    ((uint4*)As)[aslot[1]] = pa1;
    ((uint4*)As)[aslot[2]] = pa2;
    ((uint4*)As)[aslot[3]] = pa3;

    // ---- dequant + store B: 4 code bytes -> 16 f16 ----
    {
      __half2 nh = __half2half2(pn);
      int vv[4] = {pb.x, pb.y, pb.z, pb.w};
      u32 uu[8];
#pragma unroll
      for (int e = 0; e < 4; ++e) {
        uint2 lv = lut[vv[e] & 255];
        uu[2 * e] = hm2(lv.x, nh);
        uu[2 * e + 1] = hm2(lv.y, nh);
      }
      uint4* Bw = (uint4*)Bs;
#pragma unroll
      for (int cc = 0; cc < 2; ++cc) {
        int pc = (q * 2 + cc) ^ (bn & 7);
        Bw[bn * 8 + pc] = make_uint4(uu[4 * cc], uu[4 * cc + 1], uu[4 * cc + 2], uu[4 * cc + 3]);
      }
    }

    // ---- prefetch next K-slice into regs (overlaps with MFMA below) ----
    if (kt < KT - 1) {
      int ko = (kt + 1) * 64;
      pa0 = *(const uint4*)(ag[0] + ko);
      pa1 = *(const uint4*)(ag[1] + ko);
      pa2 = *(const uint4*)(ag[2] + ko);
      pa3 = *(const uint4*)(ag[3] + ko);
      pb = *(const int4*)(gB + ko);
      pn = wnp[(kt + 1) >> 1];
    }
    __syncthreads();

    // ---- compute: 2 k-substeps x (4+4 frags, 16 MFMAs) ----
#pragma unroll
    for (int ks = 0; ks < 2; ++ks) {
      f16x8 af[4], bf[4];
#pragma unroll
      for (int mt = 0; mt < 4; ++mt) {
        int row = mo + mt * 16 + l15;
        int pc = (ks * 4 + quad) ^ (row & 7);
        af[mt] = __builtin_bit_cast(f16x8, ((const uint4*)As)[row * 8 + pc]);
      }
#pragma unroll
      for (int nt = 0; nt < 4; ++nt) {
        int row = no + nt * 16 + l15;
        int pc = (ks * 4 + quad) ^ (row & 7);
        bf[nt] = __builtin_bit_cast(f16x8, ((const uint4*)Bs)[row * 8 + pc]);
      }
#pragma unroll
      for (int mt = 0; mt < 4; ++mt)
#pragma unroll
        for (int nt = 0; nt < 4; ++nt)
          acc[mt][nt] = __builtin_amdgcn_mfma_f32_16x16x32_f16(af[mt], bf[nt], acc[mt][nt], 0, 0, 0);
    }
  }

  // ---- epilogue ----
  // C/D layout: row m = quad*4 + reg, col n = lane&15  [m89/m91 verified]
  if (mode) {
    float* pp = dst + (size_t)kz * TOKENS * OUT_F;
#pragma unroll
    for (int mt = 0; mt < 4; ++mt)
#pragma unroll
      for (int nt = 0; nt < 4; ++nt)
#pragma unroll
        for (int r = 0; r < 4; ++r) {
          int mm = m0 + mo + mt * 16 + quad * 4 + r;
          int nn = n0 + no + nt * 16 + l15;
          pp[(size_t)mm * OUT_F + nn] = acc[mt][nt][r];
        }
  } else {
#pragma unroll
    for (int mt = 0; mt < 4; ++mt)
#pragma unroll
      for (int nt = 0; nt < 4; ++nt)
#pragma unroll
        for (int r = 0; r < 4; ++r) {
          int mm = m0 + mo + mt * 16 + quad * 4 + r;
          int nn = n0 + no + nt * 16 + l15;
          atomicAdd(&dst[(size_t)mm * OUT_F + nn], acc[mt][nt][r]);
        }
  }
}

extern "C" void kernel_launch(void* const* d_in, const int* in_sizes, int n_in,
                              void* d_out, int out_size, void* d_ws, size_t ws_size,
                              hipStream_t stream) {
  (void)in_sizes; (void)n_in; (void)out_size;
  const float* x = (const float*)d_in[0];
  const int* wq = (const int*)d_in[1];
  const void* wn_raw = d_in[2];
  const float* bias = (const float*)d_in[3];
  const float* la = (const float*)d_in[4];
  const float* lb = (const float*)d_in[5];
  float* out = (float*)d_out;

  u16* xb = (u16*)((char*)d_ws + XB_OFF);
  float* t = (float*)((char*)d_ws + T_OFF);
  __half* nf = (__half*)((char*)d_ws + NF_OFF);
  float* part = (float*)((char*)d_ws + PART_OFF);
  int usep = ws_size >= WS_NEED;  // constant per deployment -> graph-safe

  prep<<<1024, 256, 0, stream>>>(wn_raw, nf, x, la, xb, t);
  if (usep) {
    gemm_q2<<<dim3(OUT_F / 128, TOKENS / 256, SPLITK), 512, 0, stream>>>(xb, wq, nf, part, 1);
    finish<<<dim3(OUT_F / 256, TOKENS / 16), 256, 0, stream>>>(t, lb, bias, part, out);
  } else {
    prep2<<<dim3(OUT_F / 256, TOKENS / 16), 256, 0, stream>>>(t, lb, bias, out);
    gemm_q2<<<dim3(OUT_F / 128, TOKENS / 256, SPLITK), 512, 0, stream>>>(xb, wq, nf, out, 0);
  }
}